// Round 3
// baseline (118.693 us; speedup 1.0000x reference)
//
#include <hip/hip_runtime.h>

#define NN 8192
#define DIN 7
#define DH 8
#define DOUT 23
#define CUTOFF 3.6f
#define SLOPE 0.01f
#define CHUNK 128            // j-chunk per k3 block
#define NCHUNK (NN / CHUNK)  // 64
#define RPT 4                // rows per thread in k3

__device__ __forceinline__ float leaky(float v) { return v >= 0.0f ? v : SLOPE * v; }

// Per-node feature pipeline. MUST be the single shared implementation so k3's
// staged E/ev and k4's recomputed E/ev are bit-identical (exact diagonal cancel).
__device__ __forceinline__ void node_feats(
    const float* __restrict__ x,
    const float* __restrict__ W1, const float* __restrict__ b1,
    const float* __restrict__ W2, const float* __restrict__ b2,
    const float* __restrict__ W3, const float* __restrict__ b3,
    int n, float coord[3], float& E, float ev[7])
{
    float xi[DIN];
#pragma unroll
    for (int d = 0; d < DIN; ++d) xi[d] = x[n * DIN + d];
    coord[0] = xi[0]; coord[1] = xi[1]; coord[2] = xi[2];

    float h1[DH];
#pragma unroll
    for (int k = 0; k < DH; ++k) {
        float t = b1[k];
#pragma unroll
        for (int d = 0; d < DIN; ++d) t = fmaf(W1[k * DIN + d], xi[d], t);
        h1[k] = leaky(t);
    }
    float h2[DH];
#pragma unroll
    for (int k = 0; k < DH; ++k) {
        float t = b2[k];
#pragma unroll
        for (int d = 0; d < DH; ++d) t = fmaf(W2[k * DH + d], h1[d], t);
        h2[k] = leaky(t);
    }
    float h3[DOUT];
#pragma unroll
    for (int m = 0; m < DOUT; ++m) {
        float t = b3[m];
#pragma unroll
        for (int d = 0; d < DH; ++d) t = fmaf(W3[m * DH + d], h2[d], t);
        h3[m] = t;
    }
    float s = 0.0f;
#pragma unroll
    for (int k = 0; k < 8; ++k) s = fmaf(h3[7 + k], h3[15 + k], s);
    // |s| is O(1) (weights scaled 0.1) -> exp without max-shift is safe in fp32;
    // the softmax ratio is shift-invariant so this matches the reference.
    E = expf(s);
#pragma unroll
    for (int q = 0; q < 7; ++q) ev[q] = h3[q] * E;
}

// ---------------- K3: O(N^2) masked accumulation, fused staging, R=4 rows/thread --------
// grid (8, 64): blockIdx.x -> 1024 rows (4/thread), blockIdx.y -> 128-wide j chunk.
__global__ __launch_bounds__(256, 2) void k3_fused(
    const float* __restrict__ x,
    const float* __restrict__ W1, const float* __restrict__ b1,
    const float* __restrict__ W2, const float* __restrict__ b2,
    const float* __restrict__ W3, const float* __restrict__ b3,
    float* __restrict__ accum)
{
    __shared__ float4 sA[CHUNK];   // cx, cy, cz, E
    __shared__ float4 sB[CHUNK];   // E*vals[0..3]
    __shared__ float4 sC[CHUNK];   // E*vals[4..6], 0

    int tid = threadIdx.x;

    // stage chunk: recompute node features for this block's 128 j's
    if (tid < CHUNK) {
        int j = blockIdx.y * CHUNK + tid;
        float cj[3], E, ev[7];
        node_feats(x, W1, b1, W2, b2, W3, b3, j, cj, E, ev);
        sA[tid] = make_float4(cj[0], cj[1], cj[2], E);
        sB[tid] = make_float4(ev[0], ev[1], ev[2], ev[3]);
        sC[tid] = make_float4(ev[4], ev[5], ev[6], 0.0f);
    }

    // row coords for the 4 rows this thread owns
    int r0 = blockIdx.x * (256 * RPT) + tid;
    float cx[RPT], cy[RPT], cz[RPT];
#pragma unroll
    for (int k = 0; k < RPT; ++k) {
        int r = r0 + 256 * k;
        cx[k] = x[r * DIN + 0];
        cy[k] = x[r * DIN + 1];
        cz[k] = x[r * DIN + 2];
    }

    float acc[RPT][8];
#pragma unroll
    for (int k = 0; k < RPT; ++k)
#pragma unroll
        for (int q = 0; q < 8; ++q) acc[k][q] = 0.0f;

    __syncthreads();

#pragma unroll 4
    for (int jj = 0; jj < CHUNK; ++jj) {
        float4 cj = sA[jj];
        float4 q0 = sB[jj];
        float4 q1 = sC[jj];
#pragma unroll
        for (int k = 0; k < RPT; ++k) {
            // exact ref order: (|dx| + |dy|) + |dz|
            float t = fabsf(cx[k] - cj.x) + fabsf(cy[k] - cj.y) + fabsf(cz[k] - cj.z);
            float w = (t <= CUTOFF) ? 1.0f : 0.0f;
            acc[k][0] = fmaf(w, cj.w, acc[k][0]);
            acc[k][1] = fmaf(w, q0.x, acc[k][1]);
            acc[k][2] = fmaf(w, q0.y, acc[k][2]);
            acc[k][3] = fmaf(w, q0.z, acc[k][3]);
            acc[k][4] = fmaf(w, q0.w, acc[k][4]);
            acc[k][5] = fmaf(w, q1.x, acc[k][5]);
            acc[k][6] = fmaf(w, q1.y, acc[k][6]);
            acc[k][7] = fmaf(w, q1.z, acc[k][7]);
        }
    }

    // transposed accum [q][row]: consecutive tid -> consecutive addresses per instr
#pragma unroll
    for (int k = 0; k < RPT; ++k) {
        int r = r0 + 256 * k;
#pragma unroll
        for (int q = 0; q < 8; ++q) atomicAdd(&accum[q * NN + r], acc[k][q]);
    }
}

// ---------------- K4: recompute row features, finalize, encoder/decoder, write out -------
__global__ __launch_bounds__(256) void k4_final(
    const float* __restrict__ x,
    const float* __restrict__ W1, const float* __restrict__ b1,
    const float* __restrict__ W2, const float* __restrict__ b2,
    const float* __restrict__ W3, const float* __restrict__ b3,
    const float* __restrict__ We, const float* __restrict__ be,
    const float* __restrict__ Wd, const float* __restrict__ bd,
    const float* __restrict__ accum, float* __restrict__ out)
{
    int n = blockIdx.x * 256 + threadIdx.x;

    float cn[3], E, ev[7];
    node_feats(x, W1, b1, W2, b2, W3, b3, n, cn, E, ev);

    // remove diagonal (dist=0 always passes cutoff); bit-identical recompute -> exact
    float denom = accum[0 * NN + n] - E;
    denom = fmaxf(denom, 1e-30f);
    float inv = 1.0f / denom;

    float inp[14];
#pragma unroll
    for (int d = 0; d < DIN; ++d) inp[d] = x[n * DIN + d];
#pragma unroll
    for (int q = 0; q < 7; ++q) inp[7 + q] = (accum[(q + 1) * NN + n] - ev[q]) * inv;

    float codes[DH];
#pragma unroll
    for (int k = 0; k < DH; ++k) {
        float t = be[k];
#pragma unroll
        for (int d = 0; d < 14; ++d) t = fmaf(We[k * 14 + d], inp[d], t);
        codes[k] = leaky(t);
    }
#pragma unroll
    for (int cc = 0; cc < DIN; ++cc) {
        float t = bd[cc];
#pragma unroll
        for (int k = 0; k < DH; ++k) t = fmaf(Wd[cc * DH + k], codes[k], t);
        out[(size_t)n * DIN + cc] = t;
    }
}

extern "C" void kernel_launch(void* const* d_in, const int* in_sizes, int n_in,
                              void* d_out, int out_size, void* d_ws, size_t ws_size,
                              hipStream_t stream) {
    const float* x  = (const float*)d_in[0];
    const float* W1 = (const float*)d_in[1];
    const float* b1 = (const float*)d_in[2];
    const float* W2 = (const float*)d_in[3];
    const float* b2 = (const float*)d_in[4];
    const float* W3 = (const float*)d_in[5];
    const float* b3 = (const float*)d_in[6];
    const float* We = (const float*)d_in[7];
    const float* be = (const float*)d_in[8];
    const float* Wd = (const float*)d_in[9];
    const float* bd = (const float*)d_in[10];
    float* out = (float*)d_out;

    float* accum = (float*)d_ws;  // 8 * 8192 * 4 = 262144 B

    hipMemsetAsync(accum, 0, 8 * NN * sizeof(float), stream);
    dim3 g3(NN / (256 * RPT), NCHUNK);  // (8, 64)
    k3_fused<<<g3, 256, 0, stream>>>(x, W1, b1, W2, b2, W3, b3, accum);
    k4_final<<<32, 256, 0, stream>>>(x, W1, b1, W2, b2, W3, b3, We, be, Wd, bd, accum, out);
}